// Round 10
// baseline (155.245 us; speedup 1.0000x reference)
//
#include <hip/hip_runtime.h>
#include <cmath>

#define BBATCH 8
#define NN 128
#define DD 128      // IN_DIM
#define CC 64       // IN_DIM_E
#define HH 8
#define KK 64
#define HK 512
#define ROWS (BBATCH*NN)     // 1024
#define MATSZ (ROWS*HK)      // 524288 elements per projection matrix

typedef __attribute__((ext_vector_type(8))) short sh8;    // 8 bf16 = 4 VGPRs
typedef __attribute__((ext_vector_type(4))) float f32x4;  // MFMA C/D

static __device__ __forceinline__ unsigned short f2bf(float f) {
    union { float f; unsigned u; } v; v.f = f;
    unsigned r = v.u + 0x7fffu + ((v.u >> 16) & 1u);   // RNE
    return (unsigned short)(r >> 16);
}
static __device__ __forceinline__ float bf2f(unsigned short u) {
    union { unsigned u; float f; } v; v.u = ((unsigned)u) << 16;
    return v.f;
}

// ws layout (floats):
//   [0 .. M)      Qh fp32 [b*n][hk]
//   [M .. 2M)     Q2 fp32 [b*n][hk]
//   [2M .. 3M)    Vh fp32 [b*n][hk]
//   ushort* U = (ushort*)(ws + 3M):
//     [0 .. M)     Kt1 bf16 [b][h][j][k'] k-permuted: k' = ((k>>2)&3)*16 + (k>>4)*4 + (k&3)
//     [M .. 2M)    Kt2 bf16 same layout   (both pre-scaled by K^-0.5)
//     [2M .. +64K) Wfrag bf16 [2][8 h][8 frag][64 lane][8]  (A-operand order)

// ---------------- Kernel 1: MFMA projections + W fragment conversion (R6, proven) ----------------
__global__ __launch_bounds__(256) void proj_kernel(
    const float* __restrict__ h,
    const float* __restrict__ Wq, const float* __restrict__ Wk,
    const float* __restrict__ Wv, const float* __restrict__ Wq2,
    const float* __restrict__ Wk2,
    const float* __restrict__ We, const float* __restrict__ We2,
    float* __restrict__ ws)
{
    const int t  = threadIdx.x;
    const int bx = blockIdx.x;
    const int by = blockIdx.y;

    if (by >= 40) {
        // ---- W -> A-fragment-order bf16 ----
        const int v = by - 40;
        const float* W = v ? We2 : We;
        unsigned short* Wfrag = (unsigned short*)(ws + 3*(size_t)MATSZ) + 2*(size_t)MATSZ
                              + (size_t)v * 32768;
        const int g   = bx * 256 + t;     // 0..4095
        const int c   = g >> 6;           // 0..63
        const int sub = g & 63;
        const int hh  = sub >> 3;
        const int k0  = (sub & 7) * 8;
        float4 w0 = *(const float4*)(W + (size_t)c*HK + hh*KK + k0);
        float4 w1 = *(const float4*)(W + (size_t)c*HK + hh*KK + k0 + 4);
        float wv[8] = {w0.x,w0.y,w0.z,w0.w,w1.x,w1.y,w1.z,w1.w};
        const int cb = c >> 5, g4 = (c >> 3) & 3, jj = c & 7;
        #pragma unroll
        for (int q = 0; q < 8; ++q) {
            int k  = k0 + q;
            int mb = k >> 4, m = k & 15;
            Wfrag[(size_t)hh*4096 + (mb*2+cb)*512 + (g4*16+m)*8 + jj] = f2bf(wv[q]);
        }
        return;
    }

    // ---- MFMA tile GEMM: C[1024 x 512] = h @ W_m, tile = 64 rows x 64 cols ----
    const int m    = by >> 3;
    const int p0   = (by & 7) * 64;            // col tile base
    const float* W = (m==0)?Wq:(m==1)?Wk:(m==2)?Wv:(m==3)?Wq2:Wk2;
    const float scale = (m==1 || m==4) ? 0.125f : 1.0f;
    const int j0   = bx * 64;                  // row tile base

    const int lane = t & 63;
    const int w    = t >> 6;
    const int l15  = lane & 15;
    const int g    = lane >> 4;                // 0..3
    const int pb   = p0 + w*16;                // this wave's 16 cols

    f32x4 acc[4] = {};                         // per jb (row sub-block)
    #pragma unroll
    for (int db = 0; db < 4; ++db) {
        const int d0 = db*32 + g*8;            // this lane-group's contraction slice
        sh8 aF;
        {
            const float* wp = W + (size_t)d0*HK + pb + l15;
            #pragma unroll
            for (int q = 0; q < 8; ++q)
                aF[q] = (short)f2bf(wp[(size_t)q*HK]);
        }
        #pragma unroll
        for (int jb = 0; jb < 4; ++jb) {
            const float* hp = h + (size_t)(j0 + jb*16 + l15)*DD + d0;
            float a0[4], a1[4];
            *(float4*)a0 = *(const float4*)hp;
            *(float4*)a1 = *(const float4*)(hp + 4);
            sh8 bF;
            bF[0]=(short)f2bf(a0[0]); bF[1]=(short)f2bf(a0[1]);
            bF[2]=(short)f2bf(a0[2]); bF[3]=(short)f2bf(a0[3]);
            bF[4]=(short)f2bf(a1[0]); bF[5]=(short)f2bf(a1[1]);
            bF[6]=(short)f2bf(a1[2]); bF[7]=(short)f2bf(a1[3]);
            acc[jb] = __builtin_amdgcn_mfma_f32_16x16x32_bf16(aF, bF, acc[jb], 0, 0, 0);
        }
    }

    if (m == 1 || m == 4) {
        unsigned short* Kt = (unsigned short*)(ws + 3*(size_t)MATSZ)
                           + (m==4 ? (size_t)MATSZ : 0);
        const int hh = pb >> 6;
        const int kp = g*16 + ((pb & 63) >> 4)*4;
        #pragma unroll
        for (int jb = 0; jb < 4; ++jb) {
            int jrow = j0 + jb*16 + l15;
            int bb = jrow >> 7, n = jrow & 127;
            ushort4 u;
            u.x = f2bf(acc[jb][0]*scale); u.y = f2bf(acc[jb][1]*scale);
            u.z = f2bf(acc[jb][2]*scale); u.w = f2bf(acc[jb][3]*scale);
            *(ushort4*)(Kt + ((size_t)(bb*HH + hh)*NN + n)*KK + kp) = u;
        }
    } else {
        float* outp = ws + (m==0 ? 0 : (m==3 ? (size_t)MATSZ : 2*(size_t)MATSZ));
        #pragma unroll
        for (int jb = 0; jb < 4; ++jb) {
            int jrow = j0 + jb*16 + l15;
            float4 v = make_float4(acc[jb][0], acc[jb][1], acc[jb][2], acc[jb][3]);
            *(float4*)(outp + (size_t)jrow*HK + pb + g*4) = v;
        }
    }
}

// ---------------- Kernel 2: barrier-free pipelined MFMA attn (TI=2) + deferred reduction ----
// R9 post-mortem: phase-3 pipelining spilled (VGPR 128, WRITE 4MB) and didn't help; phase 3
// reverted to R0. This round's single change: remove the two serial __shfl_xor (DS-ops,
// ~60-120cy each, in-chain, 128/wave) from the unit loop. Each lane fire-and-forget
// ds_writes its 16-k partial to part_s[il][h][j][q4]; phase 2 sums the 4 partials during
// the exp pass. adR depends only on jl, so all q4 groups of a slot agree on the writing
// variant -> each slot written exactly once. LDS 50KB (2 blk/CU unchanged -- residency is
// register-pinned anyway, R8).
__global__ __launch_bounds__(256, 2) void attn_kernel(
    const float* __restrict__ e, const float* __restrict__ k_RW,
    const float* __restrict__ mask, const int* __restrict__ adj,
    const float* __restrict__ ws, float* __restrict__ out)
{
    __shared__ float q_s[2*2*HK];          // 8 KB  [v][il][hk]
    __shared__ float sc_s[2*HH*NN];        // 8 KB  [il][h][j]
    __shared__ float part_s[2][HH][NN][4]; // 32 KB [il][h][j][q4]
    __shared__ float kwm_s[2*NN];
    __shared__ int   ad_s[2*NN];

    const int t    = threadIdx.x;
    const int blk  = blockIdx.x;          // 512 blocks
    const int b    = blk >> 6;
    const int i0   = (blk & 63) * 2;
    const int lane = t & 63;
    const int w    = t >> 6;
    const int jl   = lane & 15;
    const int q4   = lane >> 4;           // k-quad of this lane's acc rows
    const int kq   = q4 * 4;

    const float* Vh = ws + 2*(size_t)MATSZ;
    const unsigned short* U   = (const unsigned short*)(ws + 3*(size_t)MATSZ);
    const unsigned short* Wfg = U + 2*(size_t)MATSZ;

    // ---- phase 0: e-fragments into registers; kwm/adj/Q -> LDS ----
    sh8 eF[2][2][2];   // [il][jj][cb]
    #pragma unroll
    for (int il = 0; il < 2; ++il) {
        const float* ep = e + (size_t)(b*NN + i0 + il) * (NN*CC);
        #pragma unroll
        for (int jj = 0; jj < 2; ++jj) {
            const int j = w*32 + jj*16 + jl;
            #pragma unroll
            for (int cb = 0; cb < 2; ++cb) {
                const int c0 = cb*32 + q4*8;
                float a0[4], a1[4];
                *(float4*)a0 = *(const float4*)(ep + (size_t)j*CC + c0);
                *(float4*)a1 = *(const float4*)(ep + (size_t)j*CC + c0 + 4);
                sh8 f;
                f[0]=(short)f2bf(a0[0]); f[1]=(short)f2bf(a0[1]);
                f[2]=(short)f2bf(a0[2]); f[3]=(short)f2bf(a0[3]);
                f[4]=(short)f2bf(a1[0]); f[5]=(short)f2bf(a1[1]);
                f[6]=(short)f2bf(a1[2]); f[7]=(short)f2bf(a1[3]);
                eF[il][jj][cb] = f;
            }
        }
    }
    {
        const int il = t >> 7, j = t & 127;
        kwm_s[t] = k_RW[(size_t)(b*NN + i0 + il)*NN + j] * mask[b*NN + j];
        ad_s[t]  = adj[(size_t)(b*NN + i0 + il)*NN + j];
    }
    #pragma unroll
    for (int r = 0; r < 8; ++r) {   // Q: 2048 floats
        int idx = t + 256*r;
        int v  = idx >> 10;
        int il = (idx >> 9) & 1;
        int hk = idx & 511;
        q_s[idx] = ws[(size_t)v*MATSZ + (size_t)(b*NN + i0 + il)*HK + hk];
    }
    const float maskI0 = mask[b*NN + i0];
    const float maskI1 = mask[b*NN + i0 + 1];

    // pipeline register sets (W A-frags + K frags), loaded direct global->reg
    sh8  aFA[8], aFB[8];            // [mb*2+cb]
    int4 kvA[2][2], kvB[2][2];      // [jj][half]: 16 ushorts = kv[mb=0..3][reg]
    const int j0 = w*32 + jl;       // jj=0 column
    const int j1 = j0 + 16;         // jj=1 column

#define LOADU(u_, aF_, kv_)                                                     \
    {   const int v_ = (u_) >> 3, h_ = (u_) & 7;                                \
        const sh8* wA_ = (const sh8*)(Wfg + (size_t)v_*32768 + (size_t)h_*4096);\
        _Pragma("unroll")                                                       \
        for (int f_ = 0; f_ < 8; ++f_) aF_[f_] = wA_[f_*64 + lane];             \
        const unsigned short* kt_ = U + (size_t)v_*MATSZ                        \
                                  + (size_t)(b*HH + h_)*(NN*KK) + q4*16;        \
        kv_[0][0] = ((const int4*)(kt_ + (size_t)j0*KK))[0];                    \
        kv_[0][1] = ((const int4*)(kt_ + (size_t)j0*KK))[1];                    \
        kv_[1][0] = ((const int4*)(kt_ + (size_t)j1*KK))[0];                    \
        kv_[1][1] = ((const int4*)(kt_ + (size_t)j1*KK))[1];                    \
    }

#define COMPUTE(u_, aF_, kv_)                                                   \
    {   const int v_ = (u_) >> 3, h_ = (u_) & 7;                                \
        const bool av_ = (v_ == 0);                                             \
        float kf_[2][4][4];                                                     \
        _Pragma("unroll")                                                       \
        for (int jj_ = 0; jj_ < 2; ++jj_) {                                     \
            const unsigned short* kp_ = (const unsigned short*)&kv_[jj_][0];    \
            _Pragma("unroll")                                                   \
            for (int mb_ = 0; mb_ < 4; ++mb_)                                   \
                _Pragma("unroll")                                               \
                for (int r_ = 0; r_ < 4; ++r_)                                  \
                    kf_[jj_][mb_][r_] = bf2f(kp_[mb_*4 + r_]);                  \
        }                                                                       \
        _Pragma("unroll")                                                       \
        for (int il_ = 0; il_ < 2; ++il_) {                                     \
            float4 ql_[4];                                                      \
            _Pragma("unroll")                                                   \
            for (int mb_ = 0; mb_ < 4; ++mb_)                                   \
                ql_[mb_] = *(const float4*)&q_s[(v_*2+il_)*HK + h_*KK + mb_*16 + kq]; \
            f32x4 acc_[2][4];                                                   \
            _Pragma("unroll")                                                   \
            for (int jj_ = 0; jj_ < 2; ++jj_)                                   \
                _Pragma("unroll")                                               \
                for (int mb_ = 0; mb_ < 4; ++mb_)                               \
                    acc_[jj_][mb_] = (f32x4){0.f,0.f,0.f,0.f};                  \
            _Pragma("unroll")                                                   \
            for (int jj_ = 0; jj_ < 2; ++jj_)                                   \
                _Pragma("unroll")                                               \
                for (int cb_ = 0; cb_ < 2; ++cb_) {                             \
                    sh8 bF_ = eF[il_][jj_][cb_];                                \
                    _Pragma("unroll")                                           \
                    for (int mb_ = 0; mb_ < 4; ++mb_)                           \
                        acc_[jj_][mb_] = __builtin_amdgcn_mfma_f32_16x16x32_bf16( \
                            aF_[mb_*2+cb_], bF_, acc_[jj_][mb_], 0, 0, 0);      \
                }                                                               \
            _Pragma("unroll")                                                   \
            for (int jj_ = 0; jj_ < 2; ++jj_) {                                 \
                float p_ = 0.f;                                                 \
                _Pragma("unroll")                                               \
                for (int mb_ = 0; mb_ < 4; ++mb_) {                             \
                    p_ += acc_[jj_][mb_][0] * (ql_[mb_].x * kf_[jj_][mb_][0]);  \
                    p_ += acc_[jj_][mb_][1] * (ql_[mb_].y * kf_[jj_][mb_][1]);  \
                    p_ += acc_[jj_][mb_][2] * (ql_[mb_].z * kf_[jj_][mb_][2]);  \
                    p_ += acc_[jj_][mb_][3] * (ql_[mb_].w * kf_[jj_][mb_][3]);  \
                }                                                               \
                const int jc_ = jj_ ? j1 : j0;                                  \
                if ((adR[il_][jj_] != 0) == av_)                                \
                    part_s[il_][h_][jc_][q4] = p_;                              \
            }                                                                   \
        }                                                                       \
    }

    LOADU(0, aFA, kvA)
    LOADU(1, aFB, kvB)
    __syncthreads();

    int adR[2][2];
    #pragma unroll
    for (int il = 0; il < 2; ++il) {
        adR[il][0] = ad_s[il*NN + j0];
        adR[il][1] = ad_s[il*NN + j1];
    }

    // ---- pipelined unit loop: no barriers, 1-unit prefetch distance ----
    #pragma unroll 1
    for (int u = 0; u < 16; u += 2) {
        COMPUTE(u, aFA, kvA)
        if (u + 2 < 16) LOADU(u + 2, aFA, kvA)
        COMPUTE(u + 1, aFB, kvB)
        if (u + 3 < 16) LOADU(u + 3, aFB, kvB)
    }
    __syncthreads();

    // ---- phase 2: sum q4-partials + exp * mask_i * mask_j * k_RW ----
    #pragma unroll
    for (int r = 0; r < 8; ++r) {
        int idx = t + 256*r;              // (il*8+hh)*128 + j
        int il = idx >> 10;
        int hh = (idx >> 7) & 7;
        int j  = idx & 127;
        float4 pp = *(const float4*)&part_s[il][hh][j][0];
        float s = (pp.x + pp.y) + (pp.z + pp.w);
        sc_s[idx] = __expf(s) * kwm_s[il*NN + j] * (il ? maskI1 : maskI0);
    }
    __syncthreads();

    // ---- phase 3: per-(il,head) denom + weighted V (R0 proven version) ----
    for (int hp = 0; hp < 2; ++hp) {
        const int hh = w + hp*4;
        const int r0 = hh*NN, r1 = (HH + hh)*NN;
        float d0 = sc_s[r0 + lane] + sc_s[r0 + 64 + lane];
        float d1 = sc_s[r1 + lane] + sc_s[r1 + 64 + lane];
        #pragma unroll
        for (int mm = 32; mm >= 1; mm >>= 1) {
            d0 += __shfl_xor(d0, mm);
            d1 += __shfl_xor(d1, mm);
        }
        float a0 = 0.f, a1 = 0.f;
        const float* vb = Vh + (size_t)(b*NN)*HK + hh*KK + lane;
        #pragma unroll 4
        for (int j = 0; j < NN; ++j) {
            float vf = vb[(size_t)j*HK];
            a0 += sc_s[r0 + j] * vf;
            a1 += sc_s[r1 + j] * vf;
        }
        out[(size_t)(b*NN + i0    )*HK + hh*KK + lane] = a0 / fmaxf(d0, 1e-6f);
        out[(size_t)(b*NN + i0 + 1)*HK + hh*KK + lane] = a1 / fmaxf(d1, 1e-6f);
    }
#undef LOADU
#undef COMPUTE
}

extern "C" void kernel_launch(void* const* d_in, const int* in_sizes, int n_in,
                              void* d_out, int out_size, void* d_ws, size_t ws_size,
                              hipStream_t stream) {
    const float* h    = (const float*)d_in[0];
    const float* e    = (const float*)d_in[1];
    const float* kRW  = (const float*)d_in[2];
    const float* mask = (const float*)d_in[3];
    const int*   adj  = (const int*)d_in[4];
    const float* Wq   = (const float*)d_in[5];
    const float* Wk   = (const float*)d_in[6];
    const float* Wv   = (const float*)d_in[7];
    const float* We   = (const float*)d_in[8];
    const float* Wq2  = (const float*)d_in[9];
    const float* Wk2  = (const float*)d_in[10];
    const float* We2  = (const float*)d_in[11];
    float* out = (float*)d_out;
    float* ws  = (float*)d_ws;   // 3*2MB f32 + 2*1MB bf16 + 128KB Wfrag ~= 8.2MB

    proj_kernel<<<dim3(16, 42), 256, 0, stream>>>(h, Wq, Wk, Wv, Wq2, Wk2, We, We2, ws);
    attn_kernel<<<dim3(512), 256, 0, stream>>>(e, kRW, mask, adj, ws, out);
}

// Round 11
// 148.930 us; speedup vs baseline: 1.0424x; 1.0424x over previous
//
#include <hip/hip_runtime.h>
#include <cmath>

#define BBATCH 8
#define NN 128
#define DD 128      // IN_DIM
#define CC 64       // IN_DIM_E
#define HH 8
#define KK 64
#define HK 512
#define ROWS (BBATCH*NN)     // 1024
#define MATSZ (ROWS*HK)      // 524288 elements per projection matrix

typedef __attribute__((ext_vector_type(8))) short sh8;    // 8 bf16 = 4 VGPRs
typedef __attribute__((ext_vector_type(4))) float f32x4;  // MFMA C/D

static __device__ __forceinline__ unsigned short f2bf(float f) {
    union { float f; unsigned u; } v; v.f = f;
    unsigned r = v.u + 0x7fffu + ((v.u >> 16) & 1u);   // RNE
    return (unsigned short)(r >> 16);
}
static __device__ __forceinline__ float bf2f(unsigned short u) {
    union { unsigned u; float f; } v; v.u = ((unsigned)u) << 16;
    return v.f;
}

// ws layout (floats):
//   [0 .. M)      Qh fp32 [b*n][hk]
//   [M .. 2M)     Q2 fp32 [b*n][hk]
//   [2M .. 3M)    Vh fp32 [b*n][hk]
//   ushort* U = (ushort*)(ws + 3M):
//     [0 .. M)     Kt1 bf16 [b][h][j][k'] k-permuted: k' = ((k>>2)&3)*16 + (k>>4)*4 + (k&3)
//     [M .. 2M)    Kt2 bf16 same layout   (both pre-scaled by K^-0.5)
//     [2M .. +64K) Wfrag bf16 [2][8 h][8 frag][64 lane][8]  (A-operand order)

// ---------------- Kernel 1: MFMA projections + W fragment conversion (R6, proven) ----------------
__global__ __launch_bounds__(256) void proj_kernel(
    const float* __restrict__ h,
    const float* __restrict__ Wq, const float* __restrict__ Wk,
    const float* __restrict__ Wv, const float* __restrict__ Wq2,
    const float* __restrict__ Wk2,
    const float* __restrict__ We, const float* __restrict__ We2,
    float* __restrict__ ws)
{
    const int t  = threadIdx.x;
    const int bx = blockIdx.x;
    const int by = blockIdx.y;

    if (by >= 40) {
        // ---- W -> A-fragment-order bf16 ----
        const int v = by - 40;
        const float* W = v ? We2 : We;
        unsigned short* Wfrag = (unsigned short*)(ws + 3*(size_t)MATSZ) + 2*(size_t)MATSZ
                              + (size_t)v * 32768;
        const int g   = bx * 256 + t;     // 0..4095
        const int c   = g >> 6;           // 0..63
        const int sub = g & 63;
        const int hh  = sub >> 3;
        const int k0  = (sub & 7) * 8;
        float4 w0 = *(const float4*)(W + (size_t)c*HK + hh*KK + k0);
        float4 w1 = *(const float4*)(W + (size_t)c*HK + hh*KK + k0 + 4);
        float wv[8] = {w0.x,w0.y,w0.z,w0.w,w1.x,w1.y,w1.z,w1.w};
        const int cb = c >> 5, g4 = (c >> 3) & 3, jj = c & 7;
        #pragma unroll
        for (int q = 0; q < 8; ++q) {
            int k  = k0 + q;
            int mb = k >> 4, m = k & 15;
            Wfrag[(size_t)hh*4096 + (mb*2+cb)*512 + (g4*16+m)*8 + jj] = f2bf(wv[q]);
        }
        return;
    }

    // ---- MFMA tile GEMM: C[1024 x 512] = h @ W_m, tile = 64 rows x 64 cols ----
    const int m    = by >> 3;
    const int p0   = (by & 7) * 64;            // col tile base
    const float* W = (m==0)?Wq:(m==1)?Wk:(m==2)?Wv:(m==3)?Wq2:Wk2;
    const float scale = (m==1 || m==4) ? 0.125f : 1.0f;
    const int j0   = bx * 64;                  // row tile base

    const int lane = t & 63;
    const int w    = t >> 6;
    const int l15  = lane & 15;
    const int g    = lane >> 4;                // 0..3
    const int pb   = p0 + w*16;                // this wave's 16 cols

    f32x4 acc[4] = {};                         // per jb (row sub-block)
    #pragma unroll
    for (int db = 0; db < 4; ++db) {
        const int d0 = db*32 + g*8;            // this lane-group's contraction slice
        sh8 aF;
        {
            const float* wp = W + (size_t)d0*HK + pb + l15;
            #pragma unroll
            for (int q = 0; q < 8; ++q)
                aF[q] = (short)f2bf(wp[(size_t)q*HK]);
        }
        #pragma unroll
        for (int jb = 0; jb < 4; ++jb) {
            const float* hp = h + (size_t)(j0 + jb*16 + l15)*DD + d0;
            float a0[4], a1[4];
            *(float4*)a0 = *(const float4*)hp;
            *(float4*)a1 = *(const float4*)(hp + 4);
            sh8 bF;
            bF[0]=(short)f2bf(a0[0]); bF[1]=(short)f2bf(a0[1]);
            bF[2]=(short)f2bf(a0[2]); bF[3]=(short)f2bf(a0[3]);
            bF[4]=(short)f2bf(a1[0]); bF[5]=(short)f2bf(a1[1]);
            bF[6]=(short)f2bf(a1[2]); bF[7]=(short)f2bf(a1[3]);
            acc[jb] = __builtin_amdgcn_mfma_f32_16x16x32_bf16(aF, bF, acc[jb], 0, 0, 0);
        }
    }

    if (m == 1 || m == 4) {
        unsigned short* Kt = (unsigned short*)(ws + 3*(size_t)MATSZ)
                           + (m==4 ? (size_t)MATSZ : 0);
        const int hh = pb >> 6;
        const int kp = g*16 + ((pb & 63) >> 4)*4;
        #pragma unroll
        for (int jb = 0; jb < 4; ++jb) {
            int jrow = j0 + jb*16 + l15;
            int bb = jrow >> 7, n = jrow & 127;
            ushort4 u;
            u.x = f2bf(acc[jb][0]*scale); u.y = f2bf(acc[jb][1]*scale);
            u.z = f2bf(acc[jb][2]*scale); u.w = f2bf(acc[jb][3]*scale);
            *(ushort4*)(Kt + ((size_t)(bb*HH + hh)*NN + n)*KK + kp) = u;
        }
    } else {
        float* outp = ws + (m==0 ? 0 : (m==3 ? (size_t)MATSZ : 2*(size_t)MATSZ));
        #pragma unroll
        for (int jb = 0; jb < 4; ++jb) {
            int jrow = j0 + jb*16 + l15;
            float4 v = make_float4(acc[jb][0], acc[jb][1], acc[jb][2], acc[jb][3]);
            *(float4*)(outp + (size_t)jrow*HK + pb + g*4) = v;
        }
    }
}

// ---------------- Kernel 2: barrier-free pipelined MFMA attn (TI=2, R0/R6 proven) ----------------
// R10 post-mortem: deferred reduction regressed (bank conflicts 184K from stride-4 part_s
// writes; the removed shuffles were already hidden by the co-resident wave). REVERTED to
// the R6 optimum: 2 sets, distance-1, unroll 1, in-loop shuffle reduce, R0 phase 3.
// Only residual change: phase-3 unroll 4->8 (more outstanding V loads, ~4 extra VGPRs,
// none of R9's spilling double-buffer). Ledger of falsified stalls: occupancy (R1/3/8,
// pinned ~2 waves/SIMD), DMA staging (R3-5), extra ILP (R7, spills), phase-3 pipeline
// (R9, spills), shuffle chain (R10, conflicts). This structure ~55us is near its floor.
__global__ __launch_bounds__(256, 2) void attn_kernel(
    const float* __restrict__ e, const float* __restrict__ k_RW,
    const float* __restrict__ mask, const int* __restrict__ adj,
    const float* __restrict__ ws, float* __restrict__ out)
{
    __shared__ float q_s[2*2*HK];     // 8 KB  [v][il][hk]
    __shared__ float sc_s[2*HH*NN];   // 8 KB  [il][h][j]
    __shared__ float kwm_s[2*NN];
    __shared__ int   ad_s[2*NN];

    const int t    = threadIdx.x;
    const int blk  = blockIdx.x;          // 512 blocks
    const int b    = blk >> 6;
    const int i0   = (blk & 63) * 2;
    const int lane = t & 63;
    const int w    = t >> 6;
    const int jl   = lane & 15;
    const int q4   = lane >> 4;           // k-quad of this lane's acc rows
    const int kq   = q4 * 4;

    const float* Vh = ws + 2*(size_t)MATSZ;
    const unsigned short* U   = (const unsigned short*)(ws + 3*(size_t)MATSZ);
    const unsigned short* Wfg = U + 2*(size_t)MATSZ;

    // ---- phase 0: e-fragments into registers; kwm/adj/Q -> LDS ----
    sh8 eF[2][2][2];   // [il][jj][cb]
    #pragma unroll
    for (int il = 0; il < 2; ++il) {
        const float* ep = e + (size_t)(b*NN + i0 + il) * (NN*CC);
        #pragma unroll
        for (int jj = 0; jj < 2; ++jj) {
            const int j = w*32 + jj*16 + jl;
            #pragma unroll
            for (int cb = 0; cb < 2; ++cb) {
                const int c0 = cb*32 + q4*8;
                float a0[4], a1[4];
                *(float4*)a0 = *(const float4*)(ep + (size_t)j*CC + c0);
                *(float4*)a1 = *(const float4*)(ep + (size_t)j*CC + c0 + 4);
                sh8 f;
                f[0]=(short)f2bf(a0[0]); f[1]=(short)f2bf(a0[1]);
                f[2]=(short)f2bf(a0[2]); f[3]=(short)f2bf(a0[3]);
                f[4]=(short)f2bf(a1[0]); f[5]=(short)f2bf(a1[1]);
                f[6]=(short)f2bf(a1[2]); f[7]=(short)f2bf(a1[3]);
                eF[il][jj][cb] = f;
            }
        }
    }
    {
        const int il = t >> 7, j = t & 127;
        kwm_s[t] = k_RW[(size_t)(b*NN + i0 + il)*NN + j] * mask[b*NN + j];
        ad_s[t]  = adj[(size_t)(b*NN + i0 + il)*NN + j];
    }
    #pragma unroll
    for (int r = 0; r < 8; ++r) {   // Q: 2048 floats
        int idx = t + 256*r;
        int v  = idx >> 10;
        int il = (idx >> 9) & 1;
        int hk = idx & 511;
        q_s[idx] = ws[(size_t)v*MATSZ + (size_t)(b*NN + i0 + il)*HK + hk];
    }
    const float maskI0 = mask[b*NN + i0];
    const float maskI1 = mask[b*NN + i0 + 1];

    // pipeline register sets (W A-frags + K frags), loaded direct global->reg
    sh8  aFA[8], aFB[8];            // [mb*2+cb]
    int4 kvA[2][2], kvB[2][2];      // [jj][half]: 16 ushorts = kv[mb=0..3][reg]
    const int j0 = w*32 + jl;       // jj=0 column
    const int j1 = j0 + 16;         // jj=1 column

#define LOADU(u_, aF_, kv_)                                                     \
    {   const int v_ = (u_) >> 3, h_ = (u_) & 7;                                \
        const sh8* wA_ = (const sh8*)(Wfg + (size_t)v_*32768 + (size_t)h_*4096);\
        _Pragma("unroll")                                                       \
        for (int f_ = 0; f_ < 8; ++f_) aF_[f_] = wA_[f_*64 + lane];             \
        const unsigned short* kt_ = U + (size_t)v_*MATSZ                        \
                                  + (size_t)(b*HH + h_)*(NN*KK) + q4*16;        \
        kv_[0][0] = ((const int4*)(kt_ + (size_t)j0*KK))[0];                    \
        kv_[0][1] = ((const int4*)(kt_ + (size_t)j0*KK))[1];                    \
        kv_[1][0] = ((const int4*)(kt_ + (size_t)j1*KK))[0];                    \
        kv_[1][1] = ((const int4*)(kt_ + (size_t)j1*KK))[1];                    \
    }

#define COMPUTE(u_, aF_, kv_)                                                   \
    {   const int v_ = (u_) >> 3, h_ = (u_) & 7;                                \
        const bool av_ = (v_ == 0);                                             \
        float kf_[2][4][4];                                                     \
        _Pragma("unroll")                                                       \
        for (int jj_ = 0; jj_ < 2; ++jj_) {                                     \
            const unsigned short* kp_ = (const unsigned short*)&kv_[jj_][0];    \
            _Pragma("unroll")                                                   \
            for (int mb_ = 0; mb_ < 4; ++mb_)                                   \
                _Pragma("unroll")                                               \
                for (int r_ = 0; r_ < 4; ++r_)                                  \
                    kf_[jj_][mb_][r_] = bf2f(kp_[mb_*4 + r_]);                  \
        }                                                                       \
        _Pragma("unroll")                                                       \
        for (int il_ = 0; il_ < 2; ++il_) {                                     \
            float4 ql_[4];                                                      \
            _Pragma("unroll")                                                   \
            for (int mb_ = 0; mb_ < 4; ++mb_)                                   \
                ql_[mb_] = *(const float4*)&q_s[(v_*2+il_)*HK + h_*KK + mb_*16 + kq]; \
            f32x4 acc_[2][4];                                                   \
            _Pragma("unroll")                                                   \
            for (int jj_ = 0; jj_ < 2; ++jj_)                                   \
                _Pragma("unroll")                                               \
                for (int mb_ = 0; mb_ < 4; ++mb_)                               \
                    acc_[jj_][mb_] = (f32x4){0.f,0.f,0.f,0.f};                  \
            _Pragma("unroll")                                                   \
            for (int jj_ = 0; jj_ < 2; ++jj_)                                   \
                _Pragma("unroll")                                               \
                for (int cb_ = 0; cb_ < 2; ++cb_) {                             \
                    sh8 bF_ = eF[il_][jj_][cb_];                                \
                    _Pragma("unroll")                                           \
                    for (int mb_ = 0; mb_ < 4; ++mb_)                           \
                        acc_[jj_][mb_] = __builtin_amdgcn_mfma_f32_16x16x32_bf16( \
                            aF_[mb_*2+cb_], bF_, acc_[jj_][mb_], 0, 0, 0);      \
                }                                                               \
            _Pragma("unroll")                                                   \
            for (int jj_ = 0; jj_ < 2; ++jj_) {                                 \
                float p_ = 0.f;                                                 \
                _Pragma("unroll")                                               \
                for (int mb_ = 0; mb_ < 4; ++mb_) {                             \
                    p_ += acc_[jj_][mb_][0] * (ql_[mb_].x * kf_[jj_][mb_][0]);  \
                    p_ += acc_[jj_][mb_][1] * (ql_[mb_].y * kf_[jj_][mb_][1]);  \
                    p_ += acc_[jj_][mb_][2] * (ql_[mb_].z * kf_[jj_][mb_][2]);  \
                    p_ += acc_[jj_][mb_][3] * (ql_[mb_].w * kf_[jj_][mb_][3]);  \
                }                                                               \
                p_ += __shfl_xor(p_, 16);                                       \
                p_ += __shfl_xor(p_, 32);                                       \
                const int jc_ = jj_ ? j1 : j0;                                  \
                if (lane < 16 && ((adR[il_][jj_] != 0) == av_))                 \
                    sc_s[(il_*HH + h_)*NN + jc_] = p_;                          \
            }                                                                   \
        }                                                                       \
    }

    LOADU(0, aFA, kvA)
    LOADU(1, aFB, kvB)
    __syncthreads();

    int adR[2][2];
    #pragma unroll
    for (int il = 0; il < 2; ++il) {
        adR[il][0] = ad_s[il*NN + j0];
        adR[il][1] = ad_s[il*NN + j1];
    }

    // ---- pipelined unit loop: no barriers, 1-unit prefetch distance ----
    #pragma unroll 1
    for (int u = 0; u < 16; u += 2) {
        COMPUTE(u, aFA, kvA)
        if (u + 2 < 16) LOADU(u + 2, aFA, kvA)
        COMPUTE(u + 1, aFB, kvB)
        if (u + 3 < 16) LOADU(u + 3, aFB, kvB)
    }
    __syncthreads();

    // ---- phase 2: exp * mask_i * mask_j * k_RW (global max cancels in ratio) ----
    #pragma unroll
    for (int r = 0; r < 8; ++r) {
        int idx = t + 256*r;              // (il*8+hh)*128 + j
        int il = idx >> 10;
        int j  = idx & 127;
        sc_s[idx] = __expf(sc_s[idx]) * kwm_s[il*NN + j] * (il ? maskI1 : maskI0);
    }
    __syncthreads();

    // ---- phase 3: per-(il,head) denom + weighted V (unroll 8: more loads in flight) ----
    for (int hp = 0; hp < 2; ++hp) {
        const int hh = w + hp*4;
        const int r0 = hh*NN, r1 = (HH + hh)*NN;
        float d0 = sc_s[r0 + lane] + sc_s[r0 + 64 + lane];
        float d1 = sc_s[r1 + lane] + sc_s[r1 + 64 + lane];
        #pragma unroll
        for (int mm = 32; mm >= 1; mm >>= 1) {
            d0 += __shfl_xor(d0, mm);
            d1 += __shfl_xor(d1, mm);
        }
        float a0 = 0.f, a1 = 0.f;
        const float* vb = Vh + (size_t)(b*NN)*HK + hh*KK + lane;
        #pragma unroll 8
        for (int j = 0; j < NN; ++j) {
            float vf = vb[(size_t)j*HK];
            a0 += sc_s[r0 + j] * vf;
            a1 += sc_s[r1 + j] * vf;
        }
        out[(size_t)(b*NN + i0    )*HK + hh*KK + lane] = a0 / fmaxf(d0, 1e-6f);
        out[(size_t)(b*NN + i0 + 1)*HK + hh*KK + lane] = a1 / fmaxf(d1, 1e-6f);
    }
#undef LOADU
#undef COMPUTE
}

extern "C" void kernel_launch(void* const* d_in, const int* in_sizes, int n_in,
                              void* d_out, int out_size, void* d_ws, size_t ws_size,
                              hipStream_t stream) {
    const float* h    = (const float*)d_in[0];
    const float* e    = (const float*)d_in[1];
    const float* kRW  = (const float*)d_in[2];
    const float* mask = (const float*)d_in[3];
    const int*   adj  = (const int*)d_in[4];
    const float* Wq   = (const float*)d_in[5];
    const float* Wk   = (const float*)d_in[6];
    const float* Wv   = (const float*)d_in[7];
    const float* We   = (const float*)d_in[8];
    const float* Wq2  = (const float*)d_in[9];
    const float* Wk2  = (const float*)d_in[10];
    const float* We2  = (const float*)d_in[11];
    float* out = (float*)d_out;
    float* ws  = (float*)d_ws;   // 3*2MB f32 + 2*1MB bf16 + 128KB Wfrag ~= 8.2MB

    proj_kernel<<<dim3(16, 42), 256, 0, stream>>>(h, Wq, Wk, Wv, Wq2, Wk2, We, We2, ws);
    attn_kernel<<<dim3(512), 256, 0, stream>>>(e, kRW, mask, adj, ws, out);
}

// Round 12
// 142.758 us; speedup vs baseline: 1.0875x; 1.0432x over previous
//
#include <hip/hip_runtime.h>
#include <cmath>

#define BBATCH 8
#define NN 128
#define DD 128      // IN_DIM
#define CC 64       // IN_DIM_E
#define HH 8
#define KK 64
#define HK 512
#define ROWS (BBATCH*NN)     // 1024
#define MATSZ (ROWS*HK)      // 524288 elements per projection matrix

typedef __attribute__((ext_vector_type(8))) short sh8;    // 8 bf16 = 4 VGPRs
typedef __attribute__((ext_vector_type(4))) float f32x4;  // MFMA C/D

static __device__ __forceinline__ unsigned short f2bf(float f) {
    union { float f; unsigned u; } v; v.f = f;
    unsigned r = v.u + 0x7fffu + ((v.u >> 16) & 1u);   // RNE
    return (unsigned short)(r >> 16);
}
static __device__ __forceinline__ float bf2f(unsigned short u) {
    union { unsigned u; float f; } v; v.u = ((unsigned)u) << 16;
    return v.f;
}

// ws layout (floats):
//   [0 .. M)      Qh fp32 [b*n][hk]
//   [M .. 2M)     Q2 fp32 [b*n][hk]
//   [2M .. 3M)    Vh fp32 [b*n][hk]
//   ushort* U = (ushort*)(ws + 3M):
//     [0 .. M)     Kt1 bf16 [b][h][j][k'] k-permuted: k' = ((k>>2)&3)*16 + (k>>4)*4 + (k&3)
//     [M .. 2M)    Kt2 bf16 same layout   (both pre-scaled by K^-0.5)
//     [2M .. +64K) Wfrag bf16 [2][8 h][8 frag][64 lane][8]  (A-operand order)

// ---------------- Kernel 1: MFMA projections + W fragment conversion (R6, proven) ----------------
__global__ __launch_bounds__(256) void proj_kernel(
    const float* __restrict__ h,
    const float* __restrict__ Wq, const float* __restrict__ Wk,
    const float* __restrict__ Wv, const float* __restrict__ Wq2,
    const float* __restrict__ Wk2,
    const float* __restrict__ We, const float* __restrict__ We2,
    float* __restrict__ ws)
{
    const int t  = threadIdx.x;
    const int bx = blockIdx.x;
    const int by = blockIdx.y;

    if (by >= 40) {
        // ---- W -> A-fragment-order bf16 ----
        const int v = by - 40;
        const float* W = v ? We2 : We;
        unsigned short* Wfrag = (unsigned short*)(ws + 3*(size_t)MATSZ) + 2*(size_t)MATSZ
                              + (size_t)v * 32768;
        const int g   = bx * 256 + t;     // 0..4095
        const int c   = g >> 6;           // 0..63
        const int sub = g & 63;
        const int hh  = sub >> 3;
        const int k0  = (sub & 7) * 8;
        float4 w0 = *(const float4*)(W + (size_t)c*HK + hh*KK + k0);
        float4 w1 = *(const float4*)(W + (size_t)c*HK + hh*KK + k0 + 4);
        float wv[8] = {w0.x,w0.y,w0.z,w0.w,w1.x,w1.y,w1.z,w1.w};
        const int cb = c >> 5, g4 = (c >> 3) & 3, jj = c & 7;
        #pragma unroll
        for (int q = 0; q < 8; ++q) {
            int k  = k0 + q;
            int mb = k >> 4, m = k & 15;
            Wfrag[(size_t)hh*4096 + (mb*2+cb)*512 + (g4*16+m)*8 + jj] = f2bf(wv[q]);
        }
        return;
    }

    // ---- MFMA tile GEMM: C[1024 x 512] = h @ W_m, tile = 64 rows x 64 cols ----
    const int m    = by >> 3;
    const int p0   = (by & 7) * 64;            // col tile base
    const float* W = (m==0)?Wq:(m==1)?Wk:(m==2)?Wv:(m==3)?Wq2:Wk2;
    const float scale = (m==1 || m==4) ? 0.125f : 1.0f;
    const int j0   = bx * 64;                  // row tile base

    const int lane = t & 63;
    const int w    = t >> 6;
    const int l15  = lane & 15;
    const int g    = lane >> 4;                // 0..3
    const int pb   = p0 + w*16;                // this wave's 16 cols

    f32x4 acc[4] = {};                         // per jb (row sub-block)
    #pragma unroll
    for (int db = 0; db < 4; ++db) {
        const int d0 = db*32 + g*8;            // this lane-group's contraction slice
        sh8 aF;
        {
            const float* wp = W + (size_t)d0*HK + pb + l15;
            #pragma unroll
            for (int q = 0; q < 8; ++q)
                aF[q] = (short)f2bf(wp[(size_t)q*HK]);
        }
        #pragma unroll
        for (int jb = 0; jb < 4; ++jb) {
            const float* hp = h + (size_t)(j0 + jb*16 + l15)*DD + d0;
            float a0[4], a1[4];
            *(float4*)a0 = *(const float4*)hp;
            *(float4*)a1 = *(const float4*)(hp + 4);
            sh8 bF;
            bF[0]=(short)f2bf(a0[0]); bF[1]=(short)f2bf(a0[1]);
            bF[2]=(short)f2bf(a0[2]); bF[3]=(short)f2bf(a0[3]);
            bF[4]=(short)f2bf(a1[0]); bF[5]=(short)f2bf(a1[1]);
            bF[6]=(short)f2bf(a1[2]); bF[7]=(short)f2bf(a1[3]);
            acc[jb] = __builtin_amdgcn_mfma_f32_16x16x32_bf16(aF, bF, acc[jb], 0, 0, 0);
        }
    }

    if (m == 1 || m == 4) {
        unsigned short* Kt = (unsigned short*)(ws + 3*(size_t)MATSZ)
                           + (m==4 ? (size_t)MATSZ : 0);
        const int hh = pb >> 6;
        const int kp = g*16 + ((pb & 63) >> 4)*4;
        #pragma unroll
        for (int jb = 0; jb < 4; ++jb) {
            int jrow = j0 + jb*16 + l15;
            int bb = jrow >> 7, n = jrow & 127;
            ushort4 u;
            u.x = f2bf(acc[jb][0]*scale); u.y = f2bf(acc[jb][1]*scale);
            u.z = f2bf(acc[jb][2]*scale); u.w = f2bf(acc[jb][3]*scale);
            *(ushort4*)(Kt + ((size_t)(bb*HH + hh)*NN + n)*KK + kp) = u;
        }
    } else {
        float* outp = ws + (m==0 ? 0 : (m==3 ? (size_t)MATSZ : 2*(size_t)MATSZ));
        #pragma unroll
        for (int jb = 0; jb < 4; ++jb) {
            int jrow = j0 + jb*16 + l15;
            float4 v = make_float4(acc[jb][0], acc[jb][1], acc[jb][2], acc[jb][3]);
            *(float4*)(outp + (size_t)jrow*HK + pb + g*4) = v;
        }
    }
}

// ---------------- Kernel 2: barrier-free pipelined MFMA attn (TI=2, R0/R6 proven) ----------------
// R11 post-mortem: phase-3 unroll 4->8 WON (55->48.3us, no spill) -- phase 3's V-load
// latency was partially exposed; the working lever is memory-level parallelism in serial
// phases WITHOUT pinned state (R9's explicit buffers spilled; plain unroll doesn't).
// This round: fuse phase 3's two hp iterations -> two independent load streams interleaved
// = 16 loads in flight at the same unroll; 4 denom shuffle chains interleaved. Unit loop
// untouched (2 sets, distance-1, unroll 1 -- proven optimum R0-R10).
__global__ __launch_bounds__(256, 2) void attn_kernel(
    const float* __restrict__ e, const float* __restrict__ k_RW,
    const float* __restrict__ mask, const int* __restrict__ adj,
    const float* __restrict__ ws, float* __restrict__ out)
{
    __shared__ float q_s[2*2*HK];     // 8 KB  [v][il][hk]
    __shared__ float sc_s[2*HH*NN];   // 8 KB  [il][h][j]
    __shared__ float kwm_s[2*NN];
    __shared__ int   ad_s[2*NN];

    const int t    = threadIdx.x;
    const int blk  = blockIdx.x;          // 512 blocks
    const int b    = blk >> 6;
    const int i0   = (blk & 63) * 2;
    const int lane = t & 63;
    const int w    = t >> 6;
    const int jl   = lane & 15;
    const int q4   = lane >> 4;           // k-quad of this lane's acc rows
    const int kq   = q4 * 4;

    const float* Vh = ws + 2*(size_t)MATSZ;
    const unsigned short* U   = (const unsigned short*)(ws + 3*(size_t)MATSZ);
    const unsigned short* Wfg = U + 2*(size_t)MATSZ;

    // ---- phase 0: e-fragments into registers; kwm/adj/Q -> LDS ----
    sh8 eF[2][2][2];   // [il][jj][cb]
    #pragma unroll
    for (int il = 0; il < 2; ++il) {
        const float* ep = e + (size_t)(b*NN + i0 + il) * (NN*CC);
        #pragma unroll
        for (int jj = 0; jj < 2; ++jj) {
            const int j = w*32 + jj*16 + jl;
            #pragma unroll
            for (int cb = 0; cb < 2; ++cb) {
                const int c0 = cb*32 + q4*8;
                float a0[4], a1[4];
                *(float4*)a0 = *(const float4*)(ep + (size_t)j*CC + c0);
                *(float4*)a1 = *(const float4*)(ep + (size_t)j*CC + c0 + 4);
                sh8 f;
                f[0]=(short)f2bf(a0[0]); f[1]=(short)f2bf(a0[1]);
                f[2]=(short)f2bf(a0[2]); f[3]=(short)f2bf(a0[3]);
                f[4]=(short)f2bf(a1[0]); f[5]=(short)f2bf(a1[1]);
                f[6]=(short)f2bf(a1[2]); f[7]=(short)f2bf(a1[3]);
                eF[il][jj][cb] = f;
            }
        }
    }
    {
        const int il = t >> 7, j = t & 127;
        kwm_s[t] = k_RW[(size_t)(b*NN + i0 + il)*NN + j] * mask[b*NN + j];
        ad_s[t]  = adj[(size_t)(b*NN + i0 + il)*NN + j];
    }
    #pragma unroll
    for (int r = 0; r < 8; ++r) {   // Q: 2048 floats
        int idx = t + 256*r;
        int v  = idx >> 10;
        int il = (idx >> 9) & 1;
        int hk = idx & 511;
        q_s[idx] = ws[(size_t)v*MATSZ + (size_t)(b*NN + i0 + il)*HK + hk];
    }
    const float maskI0 = mask[b*NN + i0];
    const float maskI1 = mask[b*NN + i0 + 1];

    // pipeline register sets (W A-frags + K frags), loaded direct global->reg
    sh8  aFA[8], aFB[8];            // [mb*2+cb]
    int4 kvA[2][2], kvB[2][2];      // [jj][half]: 16 ushorts = kv[mb=0..3][reg]
    const int j0 = w*32 + jl;       // jj=0 column
    const int j1 = j0 + 16;         // jj=1 column

#define LOADU(u_, aF_, kv_)                                                     \
    {   const int v_ = (u_) >> 3, h_ = (u_) & 7;                                \
        const sh8* wA_ = (const sh8*)(Wfg + (size_t)v_*32768 + (size_t)h_*4096);\
        _Pragma("unroll")                                                       \
        for (int f_ = 0; f_ < 8; ++f_) aF_[f_] = wA_[f_*64 + lane];             \
        const unsigned short* kt_ = U + (size_t)v_*MATSZ                        \
                                  + (size_t)(b*HH + h_)*(NN*KK) + q4*16;        \
        kv_[0][0] = ((const int4*)(kt_ + (size_t)j0*KK))[0];                    \
        kv_[0][1] = ((const int4*)(kt_ + (size_t)j0*KK))[1];                    \
        kv_[1][0] = ((const int4*)(kt_ + (size_t)j1*KK))[0];                    \
        kv_[1][1] = ((const int4*)(kt_ + (size_t)j1*KK))[1];                    \
    }

#define COMPUTE(u_, aF_, kv_)                                                   \
    {   const int v_ = (u_) >> 3, h_ = (u_) & 7;                                \
        const bool av_ = (v_ == 0);                                             \
        float kf_[2][4][4];                                                     \
        _Pragma("unroll")                                                       \
        for (int jj_ = 0; jj_ < 2; ++jj_) {                                     \
            const unsigned short* kp_ = (const unsigned short*)&kv_[jj_][0];    \
            _Pragma("unroll")                                                   \
            for (int mb_ = 0; mb_ < 4; ++mb_)                                   \
                _Pragma("unroll")                                               \
                for (int r_ = 0; r_ < 4; ++r_)                                  \
                    kf_[jj_][mb_][r_] = bf2f(kp_[mb_*4 + r_]);                  \
        }                                                                       \
        _Pragma("unroll")                                                       \
        for (int il_ = 0; il_ < 2; ++il_) {                                     \
            float4 ql_[4];                                                      \
            _Pragma("unroll")                                                   \
            for (int mb_ = 0; mb_ < 4; ++mb_)                                   \
                ql_[mb_] = *(const float4*)&q_s[(v_*2+il_)*HK + h_*KK + mb_*16 + kq]; \
            f32x4 acc_[2][4];                                                   \
            _Pragma("unroll")                                                   \
            for (int jj_ = 0; jj_ < 2; ++jj_)                                   \
                _Pragma("unroll")                                               \
                for (int mb_ = 0; mb_ < 4; ++mb_)                               \
                    acc_[jj_][mb_] = (f32x4){0.f,0.f,0.f,0.f};                  \
            _Pragma("unroll")                                                   \
            for (int jj_ = 0; jj_ < 2; ++jj_)                                   \
                _Pragma("unroll")                                               \
                for (int cb_ = 0; cb_ < 2; ++cb_) {                             \
                    sh8 bF_ = eF[il_][jj_][cb_];                                \
                    _Pragma("unroll")                                           \
                    for (int mb_ = 0; mb_ < 4; ++mb_)                           \
                        acc_[jj_][mb_] = __builtin_amdgcn_mfma_f32_16x16x32_bf16( \
                            aF_[mb_*2+cb_], bF_, acc_[jj_][mb_], 0, 0, 0);      \
                }                                                               \
            _Pragma("unroll")                                                   \
            for (int jj_ = 0; jj_ < 2; ++jj_) {                                 \
                float p_ = 0.f;                                                 \
                _Pragma("unroll")                                               \
                for (int mb_ = 0; mb_ < 4; ++mb_) {                             \
                    p_ += acc_[jj_][mb_][0] * (ql_[mb_].x * kf_[jj_][mb_][0]);  \
                    p_ += acc_[jj_][mb_][1] * (ql_[mb_].y * kf_[jj_][mb_][1]);  \
                    p_ += acc_[jj_][mb_][2] * (ql_[mb_].z * kf_[jj_][mb_][2]);  \
                    p_ += acc_[jj_][mb_][3] * (ql_[mb_].w * kf_[jj_][mb_][3]);  \
                }                                                               \
                p_ += __shfl_xor(p_, 16);                                       \
                p_ += __shfl_xor(p_, 32);                                       \
                const int jc_ = jj_ ? j1 : j0;                                  \
                if (lane < 16 && ((adR[il_][jj_] != 0) == av_))                 \
                    sc_s[(il_*HH + h_)*NN + jc_] = p_;                          \
            }                                                                   \
        }                                                                       \
    }

    LOADU(0, aFA, kvA)
    LOADU(1, aFB, kvB)
    __syncthreads();

    int adR[2][2];
    #pragma unroll
    for (int il = 0; il < 2; ++il) {
        adR[il][0] = ad_s[il*NN + j0];
        adR[il][1] = ad_s[il*NN + j1];
    }

    // ---- pipelined unit loop: no barriers, 1-unit prefetch distance ----
    #pragma unroll 1
    for (int u = 0; u < 16; u += 2) {
        COMPUTE(u, aFA, kvA)
        if (u + 2 < 16) LOADU(u + 2, aFA, kvA)
        COMPUTE(u + 1, aFB, kvB)
        if (u + 3 < 16) LOADU(u + 3, aFB, kvB)
    }
    __syncthreads();

    // ---- phase 2: exp * mask_i * mask_j * k_RW (global max cancels in ratio) ----
    #pragma unroll
    for (int r = 0; r < 8; ++r) {
        int idx = t + 256*r;              // (il*8+hh)*128 + j
        int il = idx >> 10;
        int j  = idx & 127;
        sc_s[idx] = __expf(sc_s[idx]) * kwm_s[il*NN + j] * (il ? maskI1 : maskI0);
    }
    __syncthreads();

    // ---- phase 3: both heads fused -- 2 independent V streams, 16 loads in flight ----
    {
        const int hhA = w, hhB = w + 4;
        const int rA0 = hhA*NN, rA1 = (HH + hhA)*NN;
        const int rB0 = hhB*NN, rB1 = (HH + hhB)*NN;
        float dA0 = sc_s[rA0 + lane] + sc_s[rA0 + 64 + lane];
        float dA1 = sc_s[rA1 + lane] + sc_s[rA1 + 64 + lane];
        float dB0 = sc_s[rB0 + lane] + sc_s[rB0 + 64 + lane];
        float dB1 = sc_s[rB1 + lane] + sc_s[rB1 + 64 + lane];
        #pragma unroll
        for (int mm = 32; mm >= 1; mm >>= 1) {
            dA0 += __shfl_xor(dA0, mm);
            dA1 += __shfl_xor(dA1, mm);
            dB0 += __shfl_xor(dB0, mm);
            dB1 += __shfl_xor(dB1, mm);
        }
        float aA0 = 0.f, aA1 = 0.f, aB0 = 0.f, aB1 = 0.f;
        const float* vbA = Vh + (size_t)(b*NN)*HK + hhA*KK + lane;
        const float* vbB = vbA + 4*KK;
        #pragma unroll 8
        for (int j = 0; j < NN; ++j) {
            float vfA = vbA[(size_t)j*HK];
            float vfB = vbB[(size_t)j*HK];
            aA0 += sc_s[rA0 + j] * vfA;
            aA1 += sc_s[rA1 + j] * vfA;
            aB0 += sc_s[rB0 + j] * vfB;
            aB1 += sc_s[rB1 + j] * vfB;
        }
        out[(size_t)(b*NN + i0    )*HK + hhA*KK + lane] = aA0 / fmaxf(dA0, 1e-6f);
        out[(size_t)(b*NN + i0 + 1)*HK + hhA*KK + lane] = aA1 / fmaxf(dA1, 1e-6f);
        out[(size_t)(b*NN + i0    )*HK + hhB*KK + lane] = aB0 / fmaxf(dB0, 1e-6f);
        out[(size_t)(b*NN + i0 + 1)*HK + hhB*KK + lane] = aB1 / fmaxf(dB1, 1e-6f);
    }
#undef LOADU
#undef COMPUTE
}

extern "C" void kernel_launch(void* const* d_in, const int* in_sizes, int n_in,
                              void* d_out, int out_size, void* d_ws, size_t ws_size,
                              hipStream_t stream) {
    const float* h    = (const float*)d_in[0];
    const float* e    = (const float*)d_in[1];
    const float* kRW  = (const float*)d_in[2];
    const float* mask = (const float*)d_in[3];
    const int*   adj  = (const int*)d_in[4];
    const float* Wq   = (const float*)d_in[5];
    const float* Wk   = (const float*)d_in[6];
    const float* Wv   = (const float*)d_in[7];
    const float* We   = (const float*)d_in[8];
    const float* Wq2  = (const float*)d_in[9];
    const float* Wk2  = (const float*)d_in[10];
    const float* We2  = (const float*)d_in[11];
    float* out = (float*)d_out;
    float* ws  = (float*)d_ws;   // 3*2MB f32 + 2*1MB bf16 + 128KB Wfrag ~= 8.2MB

    proj_kernel<<<dim3(16, 42), 256, 0, stream>>>(h, Wq, Wk, Wv, Wq2, Wk2, We, We2, ws);
    attn_kernel<<<dim3(512), 256, 0, stream>>>(e, kRW, mask, adj, ws, out);
}